// Round 1
// 492.049 us; speedup vs baseline: 1.0228x; 1.0228x over previous
//
#include <hip/hip_runtime.h>
#include <cmath>

#define NB 1024   // batches
#define NN 1024   // rows
#define MM 64     // cols
#define NT 512    // threads per block (8 waves -> 4 blocks/CU = 32 waves/CU)
#define NW (NT / 64)

typedef float f32x4 __attribute__((ext_vector_type(4)));

// Block-wide sum over NT threads (NW waves). Trailing barrier protects s_tmp reuse.
__device__ __forceinline__ float block_sum(float v, float* s_tmp) {
    #pragma unroll
    for (int off = 32; off > 0; off >>= 1) v += __shfl_xor(v, off, 64);
    if ((threadIdx.x & 63) == 0) s_tmp[threadIdx.x >> 6] = v;
    __syncthreads();
    float r = 0.0f;
    #pragma unroll
    for (int i = 0; i < NW; ++i) r += s_tmp[i];
    __syncthreads();
    return r;
}

__device__ __forceinline__ float block_max(float v, float* s_tmp) {
    #pragma unroll
    for (int off = 32; off > 0; off >>= 1) v = fmaxf(v, __shfl_xor(v, off, 64));
    if ((threadIdx.x & 63) == 0) s_tmp[threadIdx.x >> 6] = v;
    __syncthreads();
    float r = s_tmp[0];
    #pragma unroll
    for (int i = 1; i < NW; ++i) r = fmaxf(r, s_tmp[i]);
    __syncthreads();
    return r;
}

__global__ void __launch_bounds__(NT, 8) ntm_fused(
    const float* __restrict__ memory,
    const float* __restrict__ k,
    const float* __restrict__ beta,
    const float* __restrict__ g,
    const float* __restrict__ s,
    const float* __restrict__ gamma,
    const float* __restrict__ w_prev,
    const float* __restrict__ e,
    const float* __restrict__ a,
    float* __restrict__ out)
{
    __shared__ float  s_wg[NN];     // scores, then interpolated wg
    __shared__ float  s_w[NN];      // final sharpened+normalized weights
    __shared__ float  s_k[MM];
    __shared__ float  s_tmp[NW];
    __shared__ f32x4  s_red[NW * 16];

    const int b    = blockIdx.x;
    const int t    = threadIdx.x;
    const int cg   = t & 15;   // column group: cols [4*cg, 4*cg+3]
    const int rg   = t >> 4;   // row subgroup: 0..31
    const int wid  = t >> 6;   // wave id: 0..NW-1
    const int lane = t & 63;

    const float* memb = memory + (size_t)b * NN * MM;
    float*       outb = out    + (size_t)b * (NN + 1) * MM;

    // --- early prefetch of small per-batch operands (latency hides under pass 1) ---
    const float bet = beta[b];
    const float gb  = g[b];
    const float s0  = s[b * 3 + 0], s1 = s[b * 3 + 1], s2 = s[b * 3 + 2];
    const float gam = gamma[b];
    const float wp0 = w_prev[b * NN + t];
    const float wp1 = w_prev[b * NN + t + 512];

    // --- stage k_e, compute ||k_e|| ---
    if (t < MM) s_k[t] = k[b * MM + t] + 1e-16f;
    __syncthreads();
    float kq = (t < MM) ? s_k[t] * s_k[t] : 0.0f;
    float kden = fmaxf(sqrtf(block_sum(kq, s_tmp)), 1e-8f);
    const f32x4 k4 = ((const f32x4*)s_k)[cg];

    // --- pass 1: cosine-sim scores (16 lanes per row, 4 cols each) ---
    #pragma unroll 4
    for (int it = 0; it < NN / 32; ++it) {
        int n = it * 32 + rg;
        f32x4 m4 = *(const f32x4*)(memb + (size_t)n * MM + 4 * cg);
        float ex = m4.x + 1e-16f, ey = m4.y + 1e-16f;
        float ez = m4.z + 1e-16f, ew = m4.w + 1e-16f;
        float d = ex * k4.x + ey * k4.y + ez * k4.z + ew * k4.w;
        float q = ex * ex + ey * ey + ez * ez + ew * ew;
        #pragma unroll
        for (int off = 8; off > 0; off >>= 1) {
            d += __shfl_xor(d, off, 64);
            q += __shfl_xor(q, off, 64);
        }
        if (cg == 0) {
            float denom = fmaxf(sqrtf(q), 1e-8f) * kden;
            s_wg[n] = bet * d / denom;
        }
    }
    __syncthreads();

    // prefetch e/a fragments now; latency hides under softmax/shift section
    const f32x4 e4 = *(const f32x4*)(e + b * MM + 4 * cg);
    const f32x4 a4 = *(const f32x4*)(a + b * MM + 4 * cg);

    // --- softmax over N (each thread owns indices t, t+512) ---
    float sc0 = s_wg[t], sc1 = s_wg[t + 512];
    float mx = block_max(fmaxf(sc0, sc1), s_tmp);
    float e0 = __expf(sc0 - mx), e1 = __expf(sc1 - mx);
    float inv_esum = 1.0f / block_sum(e0 + e1, s_tmp);

    // --- interpolate ---
    const float omg = 1.0f - gb;
    s_wg[t]       = gb * e0 * inv_esum + omg * wp0;
    s_wg[t + 512] = gb * e1 * inv_esum + omg * wp1;
    __syncthreads();

    // --- shift (3-tap circular) + sharpen ---
    float wv0, wv1;
    {
        int n  = t;
        int nm = (n == 0) ? NN - 1 : n - 1;
        float wh = s0 * s_wg[nm] + s1 * s_wg[n] + s2 * s_wg[n + 1];
        wv0 = powf(wh, gam);
    }
    {
        int n  = t + 512;
        int np = (n == NN - 1) ? 0 : n + 1;
        float wh = s0 * s_wg[n - 1] + s1 * s_wg[n] + s2 * s_wg[np];
        wv1 = powf(wh, gam);
    }
    float winv = 1.0f / (block_sum(wv0 + wv1, s_tmp) + 1e-16f);
    s_w[t]       = wv0 * winv;
    s_w[t + 512] = wv1 * winv;
    __syncthreads();

    // --- pass 2: read + erase/add update (nontemporal stores: output never re-read) ---
    f32x4 acc = {0.f, 0.f, 0.f, 0.f};
    #pragma unroll 4
    for (int it = 0; it < NN / 32; ++it) {
        int n = it * 32 + rg;
        f32x4 m4 = *(const f32x4*)(memb + (size_t)n * MM + 4 * cg);
        float wn = s_w[n];
        acc.x += wn * m4.x; acc.y += wn * m4.y;
        acc.z += wn * m4.z; acc.w += wn * m4.w;
        f32x4 o;
        o.x = m4.x * (1.0f - wn * e4.x) + wn * a4.x;
        o.y = m4.y * (1.0f - wn * e4.y) + wn * a4.y;
        o.z = m4.z * (1.0f - wn * e4.z) + wn * a4.z;
        o.w = m4.w * (1.0f - wn * e4.w) + wn * a4.w;
        __builtin_nontemporal_store(o, (f32x4*)(outb + (size_t)(n + 1) * MM + 4 * cg));
    }

    // reduce read accumulator: in-wave over the 4 row-subgroups, then across waves
    #pragma unroll
    for (int off = 16; off <= 32; off <<= 1) {
        acc.x += __shfl_xor(acc.x, off, 64);
        acc.y += __shfl_xor(acc.y, off, 64);
        acc.z += __shfl_xor(acc.z, off, 64);
        acc.w += __shfl_xor(acc.w, off, 64);
    }
    if (lane < 16) s_red[wid * 16 + lane] = acc;
    __syncthreads();
    if (t < 16) {
        f32x4 r = {0.f, 0.f, 0.f, 0.f};
        #pragma unroll
        for (int wv = 0; wv < NW; ++wv) {
            f32x4 v = s_red[wv * 16 + t];
            r.x += v.x; r.y += v.y; r.z += v.z; r.w += v.w;
        }
        __builtin_nontemporal_store(r, (f32x4*)(outb + 4 * t));   // row 0 = read
    }
}

extern "C" void kernel_launch(void* const* d_in, const int* in_sizes, int n_in,
                              void* d_out, int out_size, void* d_ws, size_t ws_size,
                              hipStream_t stream) {
    ntm_fused<<<NB, NT, 0, stream>>>(
        (const float*)d_in[0],  // memory (B,N,M)
        (const float*)d_in[1],  // k      (B,M)
        (const float*)d_in[2],  // beta   (B,1)
        (const float*)d_in[3],  // g      (B,1)
        (const float*)d_in[4],  // s      (B,3)
        (const float*)d_in[5],  // gamma  (B,1)
        (const float*)d_in[6],  // w_prev (B,N)
        (const float*)d_in[7],  // e      (B,M)
        (const float*)d_in[8],  // a      (B,M)
        (float*)d_out);
}

// Round 2
// 479.698 us; speedup vs baseline: 1.0491x; 1.0257x over previous
//
#include <hip/hip_runtime.h>
#include <cmath>

#define NB 1024   // batches
#define NN 1024   // rows
#define MM 64     // cols
#define NT 512    // threads per block
#define NW (NT / 64)

typedef float f32x4 __attribute__((ext_vector_type(4)));

// Block-wide sum over NT threads (NW waves). Trailing barrier protects s_tmp reuse.
__device__ __forceinline__ float block_sum(float v, float* s_tmp) {
    #pragma unroll
    for (int off = 32; off > 0; off >>= 1) v += __shfl_xor(v, off, 64);
    if ((threadIdx.x & 63) == 0) s_tmp[threadIdx.x >> 6] = v;
    __syncthreads();
    float r = 0.0f;
    #pragma unroll
    for (int i = 0; i < NW; ++i) r += s_tmp[i];
    __syncthreads();
    return r;
}

__device__ __forceinline__ float block_max(float v, float* s_tmp) {
    #pragma unroll
    for (int off = 32; off > 0; off >>= 1) v = fmaxf(v, __shfl_xor(v, off, 64));
    if ((threadIdx.x & 63) == 0) s_tmp[threadIdx.x >> 6] = v;
    __syncthreads();
    float r = s_tmp[0];
    #pragma unroll
    for (int i = 1; i < NW; ++i) r = fmaxf(r, s_tmp[i]);
    __syncthreads();
    return r;
}

// softmax + interpolate + shift + sharpen: s_sc (scores) -> s_w (weights).
// s_sc is free for reuse after return. Ends with a barrier.
__device__ __forceinline__ void middle(
    float wp0, float wp1, float gb, float s0, float s1, float s2, float gam,
    float* s_sc, float* s_w, float* s_tmp)
{
    const int t = threadIdx.x;
    float sc0 = s_sc[t], sc1 = s_sc[t + 512];
    float mx = block_max(fmaxf(sc0, sc1), s_tmp);
    float e0 = __expf(sc0 - mx), e1 = __expf(sc1 - mx);
    float inv = 1.0f / block_sum(e0 + e1, s_tmp);
    const float omg = 1.0f - gb;
    s_sc[t]       = gb * e0 * inv + omg * wp0;
    s_sc[t + 512] = gb * e1 * inv + omg * wp1;
    __syncthreads();
    float wv0, wv1;
    {
        int nm = (t == 0) ? NN - 1 : t - 1;
        wv0 = powf(s0 * s_sc[nm] + s1 * s_sc[t] + s2 * s_sc[t + 1], gam);
    }
    {
        int n = t + 512;
        int np = (n == NN - 1) ? 0 : n + 1;
        wv1 = powf(s0 * s_sc[n - 1] + s1 * s_sc[n] + s2 * s_sc[np], gam);
    }
    float winv = 1.0f / (block_sum(wv0 + wv1, s_tmp) + 1e-16f);
    s_w[t]       = wv0 * winv;
    s_w[t + 512] = wv1 * winv;
    __syncthreads();
}

// cosine-sim scores for one batch: memb -> s_sc (read-only HBM stream)
__device__ __forceinline__ void score_rows(
    const float* __restrict__ memb, f32x4 k4, float kden, float bet,
    float* s_sc, int cg, int rg)
{
    #pragma unroll 4
    for (int it = 0; it < NN / 32; ++it) {
        int n = it * 32 + rg;
        f32x4 m4 = *(const f32x4*)(memb + (size_t)n * MM + 4 * cg);
        float ex = m4.x + 1e-16f, ey = m4.y + 1e-16f;
        float ez = m4.z + 1e-16f, ew = m4.w + 1e-16f;
        float d = ex * k4.x + ey * k4.y + ez * k4.z + ew * k4.w;
        float q = ex * ex + ey * ey + ez * ez + ew * ew;
        #pragma unroll
        for (int off = 8; off > 0; off >>= 1) {
            d += __shfl_xor(d, off, 64);
            q += __shfl_xor(q, off, 64);
        }
        if (cg == 0) s_sc[n] = bet * d / (fmaxf(sqrtf(q), 1e-8f) * kden);
    }
}

// erase/add update + read accumulation for one batch (L3 read + HBM write)
__device__ __forceinline__ f32x4 update_rows(
    const float* __restrict__ memb, float* __restrict__ outb,
    const float* s_w, f32x4 e4, f32x4 a4, int cg, int rg)
{
    f32x4 acc = {0.f, 0.f, 0.f, 0.f};
    #pragma unroll 4
    for (int it = 0; it < NN / 32; ++it) {
        int n = it * 32 + rg;
        f32x4 m4 = *(const f32x4*)(memb + (size_t)n * MM + 4 * cg);
        float wn = s_w[n];
        acc.x += wn * m4.x; acc.y += wn * m4.y;
        acc.z += wn * m4.z; acc.w += wn * m4.w;
        f32x4 o;
        o.x = m4.x * (1.0f - wn * e4.x) + wn * a4.x;
        o.y = m4.y * (1.0f - wn * e4.y) + wn * a4.y;
        o.z = m4.z * (1.0f - wn * e4.z) + wn * a4.z;
        o.w = m4.w * (1.0f - wn * e4.w) + wn * a4.w;
        __builtin_nontemporal_store(o, (f32x4*)(outb + (size_t)(n + 1) * MM + 4 * cg));
    }
    return acc;
}

// Pipelined stage: HBM-read mem[b1] (scores b1) overlapped with
// L3-read mem[b0] + HBM-write out[b0] (update b0).
__device__ __forceinline__ f32x4 fused_rows(
    const float* __restrict__ memb0, const float* __restrict__ memb1,
    float* __restrict__ outb0, const float* s_w0, float* s_sc1,
    f32x4 e40, f32x4 a40, f32x4 k41, float kden1, float bet1, int cg, int rg)
{
    f32x4 acc = {0.f, 0.f, 0.f, 0.f};
    #pragma unroll 2
    for (int it = 0; it < NN / 32; ++it) {
        int n = it * 32 + rg;
        // issue the HBM load first (long latency), L3 load second
        f32x4 m1 = *(const f32x4*)(memb1 + (size_t)n * MM + 4 * cg);
        f32x4 m0 = *(const f32x4*)(memb0 + (size_t)n * MM + 4 * cg);
        // update(b0) first: short-latency operands, keeps write stream flowing
        float wn = s_w0[n];
        acc.x += wn * m0.x; acc.y += wn * m0.y;
        acc.z += wn * m0.z; acc.w += wn * m0.w;
        f32x4 o;
        o.x = m0.x * (1.0f - wn * e40.x) + wn * a40.x;
        o.y = m0.y * (1.0f - wn * e40.y) + wn * a40.y;
        o.z = m0.z * (1.0f - wn * e40.z) + wn * a40.z;
        o.w = m0.w * (1.0f - wn * e40.w) + wn * a40.w;
        __builtin_nontemporal_store(o, (f32x4*)(outb0 + (size_t)(n + 1) * MM + 4 * cg));
        // scores(b1)
        float ex = m1.x + 1e-16f, ey = m1.y + 1e-16f;
        float ez = m1.z + 1e-16f, ew = m1.w + 1e-16f;
        float d = ex * k41.x + ey * k41.y + ez * k41.z + ew * k41.w;
        float q = ex * ex + ey * ey + ez * ez + ew * ew;
        #pragma unroll
        for (int off = 8; off > 0; off >>= 1) {
            d += __shfl_xor(d, off, 64);
            q += __shfl_xor(q, off, 64);
        }
        if (cg == 0) s_sc1[n] = bet1 * d / (fmaxf(sqrtf(q), 1e-8f) * kden1);
    }
    return acc;
}

// cross-wave reduction of the read row; writes row 0 of outb. Ends with barrier.
__device__ __forceinline__ void reduce_read(
    f32x4 acc, float* __restrict__ outb, f32x4* s_red)
{
    const int t = threadIdx.x, wid = t >> 6, lane = t & 63;
    #pragma unroll
    for (int off = 16; off <= 32; off <<= 1) {
        acc.x += __shfl_xor(acc.x, off, 64);
        acc.y += __shfl_xor(acc.y, off, 64);
        acc.z += __shfl_xor(acc.z, off, 64);
        acc.w += __shfl_xor(acc.w, off, 64);
    }
    if (lane < 16) s_red[wid * 16 + lane] = acc;
    __syncthreads();
    if (t < 16) {
        f32x4 r = {0.f, 0.f, 0.f, 0.f};
        #pragma unroll
        for (int wv = 0; wv < NW; ++wv) {
            f32x4 v = s_red[wv * 16 + t];
            r.x += v.x; r.y += v.y; r.z += v.z; r.w += v.w;
        }
        __builtin_nontemporal_store(r, (f32x4*)(outb + 4 * t));
    }
    __syncthreads();
}

__global__ void __launch_bounds__(NT, 4) ntm_fused(
    const float* __restrict__ memory,
    const float* __restrict__ k,
    const float* __restrict__ beta,
    const float* __restrict__ g,
    const float* __restrict__ s,
    const float* __restrict__ gamma,
    const float* __restrict__ w_prev,
    const float* __restrict__ e,
    const float* __restrict__ a,
    float* __restrict__ out)
{
    __shared__ float  s_sc[NN];
    __shared__ float  s_w[NN];
    __shared__ float  s_k[MM];
    __shared__ float  s_tmp[NW];
    __shared__ f32x4  s_red[NW * 16];

    const int t  = threadIdx.x;
    const int cg = t & 15;
    const int rg = t >> 4;
    const int b0 = 2 * blockIdx.x, b1 = b0 + 1;

    const float* memb0 = memory + (size_t)b0 * NN * MM;
    const float* memb1 = memory + (size_t)b1 * NN * MM;
    float*       outb0 = out    + (size_t)b0 * (NN + 1) * MM;
    float*       outb1 = out    + (size_t)b1 * (NN + 1) * MM;

    // prefetch b0 small operands
    const float bet0 = beta[b0], gb0 = g[b0];
    const float s00 = s[b0 * 3 + 0], s01 = s[b0 * 3 + 1], s02 = s[b0 * 3 + 2];
    const float gam0 = gamma[b0];
    const float wp00 = w_prev[(size_t)b0 * NN + t];
    const float wp01 = w_prev[(size_t)b0 * NN + t + 512];
    const f32x4 e40 = *(const f32x4*)(e + b0 * MM + 4 * cg);
    const f32x4 a40 = *(const f32x4*)(a + b0 * MM + 4 * cg);

    // --- k(b0) staging + norm ---
    if (t < MM) s_k[t] = k[b0 * MM + t] + 1e-16f;
    float kq0 = (t < MM) ? s_k[t] * s_k[t] : 0.0f;
    float kden0 = fmaxf(sqrtf(block_sum(kq0, s_tmp)), 1e-8f);   // barrier orders s_k
    const f32x4 k40 = ((const f32x4*)s_k)[cg];

    // --- stage 1: read-only scores(b0) ---
    score_rows(memb0, k40, kden0, bet0, s_sc, cg, rg);
    __syncthreads();

    middle(wp00, wp01, gb0, s00, s01, s02, gam0, s_sc, s_w, s_tmp);

    // --- k(b1) staging + norm (s_k reusable: k40 is in regs) ---
    if (t < MM) s_k[t] = k[b1 * MM + t] + 1e-16f;
    float kq1 = (t < MM) ? s_k[t] * s_k[t] : 0.0f;
    float kden1 = fmaxf(sqrtf(block_sum(kq1, s_tmp)), 1e-8f);
    const f32x4 k41 = ((const f32x4*)s_k)[cg];

    const float bet1 = beta[b1], gb1 = g[b1];
    const float s10 = s[b1 * 3 + 0], s11 = s[b1 * 3 + 1], s12 = s[b1 * 3 + 2];
    const float gam1 = gamma[b1];
    const float wp10 = w_prev[(size_t)b1 * NN + t];
    const float wp11 = w_prev[(size_t)b1 * NN + t + 512];
    const f32x4 e41 = *(const f32x4*)(e + b1 * MM + 4 * cg);
    const f32x4 a41 = *(const f32x4*)(a + b1 * MM + 4 * cg);

    // --- stage 2 (mixed R+W): update(b0) writes overlap scores(b1) reads ---
    f32x4 acc0 = fused_rows(memb0, memb1, outb0, s_w, s_sc,
                            e40, a40, k41, kden1, bet1, cg, rg);
    __syncthreads();
    reduce_read(acc0, outb0, s_red);

    middle(wp10, wp11, gb1, s10, s11, s12, gam1, s_sc, s_w, s_tmp);

    // --- stage 3: write-dominated update(b1) (memory re-read hits L3) ---
    f32x4 acc1 = update_rows(memb1, outb1, s_w, e41, a41, cg, rg);
    reduce_read(acc1, outb1, s_red);
}

extern "C" void kernel_launch(void* const* d_in, const int* in_sizes, int n_in,
                              void* d_out, int out_size, void* d_ws, size_t ws_size,
                              hipStream_t stream) {
    ntm_fused<<<NB / 2, NT, 0, stream>>>(
        (const float*)d_in[0],  // memory (B,N,M)
        (const float*)d_in[1],  // k      (B,M)
        (const float*)d_in[2],  // beta   (B,1)
        (const float*)d_in[3],  // g      (B,1)
        (const float*)d_in[4],  // s      (B,3)
        (const float*)d_in[5],  // gamma  (B,1)
        (const float*)d_in[6],  // w_prev (B,N)
        (const float*)d_in[7],  // e      (B,M)
        (const float*)d_in[8],  // a      (B,M)
        (float*)d_out);
}

// Round 3
// 471.538 us; speedup vs baseline: 1.0673x; 1.0173x over previous
//
#include <hip/hip_runtime.h>
#include <cmath>

#define NB 1024   // batches
#define NN 1024   // rows
#define MM 64     // cols
#define NT 512    // threads per block
#define NW (NT / 64)
#define ITS (NN / 32)   // 32 row-iterations; each covers 32 rows (rg = 0..31)

typedef float f32x4 __attribute__((ext_vector_type(4)));

// Block-wide sum over NT threads (NW waves). Trailing barrier protects s_tmp reuse.
__device__ __forceinline__ float block_sum(float v, float* s_tmp) {
    #pragma unroll
    for (int off = 32; off > 0; off >>= 1) v += __shfl_xor(v, off, 64);
    if ((threadIdx.x & 63) == 0) s_tmp[threadIdx.x >> 6] = v;
    __syncthreads();
    float r = 0.0f;
    #pragma unroll
    for (int i = 0; i < NW; ++i) r += s_tmp[i];
    __syncthreads();
    return r;
}

__device__ __forceinline__ float block_max(float v, float* s_tmp) {
    #pragma unroll
    for (int off = 32; off > 0; off >>= 1) v = fmaxf(v, __shfl_xor(v, off, 64));
    if ((threadIdx.x & 63) == 0) s_tmp[threadIdx.x >> 6] = v;
    __syncthreads();
    float r = s_tmp[0];
    #pragma unroll
    for (int i = 1; i < NW; ++i) r = fmaxf(r, s_tmp[i]);
    __syncthreads();
    return r;
}

__global__ void __launch_bounds__(NT, 2) ntm_fused(
    const float* __restrict__ memory,
    const float* __restrict__ k,
    const float* __restrict__ beta,
    const float* __restrict__ g,
    const float* __restrict__ s,
    const float* __restrict__ gamma,
    const float* __restrict__ w_prev,
    const float* __restrict__ e,
    const float* __restrict__ a,
    float* __restrict__ out)
{
    __shared__ float  s_sc[NN];     // scores, then interpolated wg
    __shared__ float  s_w[NN];      // final sharpened+normalized weights
    __shared__ float  s_k[MM];
    __shared__ float  s_tmp[NW];
    __shared__ f32x4  s_red[NW * 16];

    const int t  = threadIdx.x;
    const int cg = t & 15;   // column group: cols [4*cg, 4*cg+3]
    const int rg = t >> 4;   // row subgroup: 0..31
    const int b  = blockIdx.x;

    const float* memb = memory + (size_t)b * NN * MM;
    float*       outb = out    + (size_t)b * (NN + 1) * MM;

    // small per-batch operands (latency hides under pass-1 loads)
    const float bet = beta[b], gb = g[b];
    const float s0 = s[b * 3 + 0], s1 = s[b * 3 + 1], s2 = s[b * 3 + 2];
    const float gam = gamma[b];
    const float wp0 = w_prev[(size_t)b * NN + t];
    const float wp1 = w_prev[(size_t)b * NN + t + 512];
    const f32x4 e4 = *(const f32x4*)(e + b * MM + 4 * cg);
    const f32x4 a4 = *(const f32x4*)(a + b * MM + 4 * cg);

    // --- register cache: issue ALL slice loads up front (max MLP).
    // 32 x f32x4 = 128 VGPRs per thread; block covers the full 256 KB slice.
    f32x4 mc[ITS];
    #pragma unroll
    for (int it = 0; it < ITS; ++it) {
        int n = it * 32 + rg;
        mc[it] = __builtin_nontemporal_load(
            (const f32x4*)(memb + (size_t)n * MM + 4 * cg));
    }

    // --- k staging + ||k_e|| (overlaps with in-flight loads) ---
    if (t < MM) s_k[t] = k[b * MM + t] + 1e-16f;
    float kq = (t < MM) ? s_k[t] * s_k[t] : 0.0f;
    float kden = fmaxf(sqrtf(block_sum(kq, s_tmp)), 1e-8f);  // barrier orders s_k
    const f32x4 k4 = ((const f32x4*)s_k)[cg];

    // --- pass 1: cosine-sim scores from the register cache ---
    #pragma unroll
    for (int it = 0; it < ITS; ++it) {
        int n = it * 32 + rg;
        f32x4 m4 = mc[it];
        float ex = m4.x + 1e-16f, ey = m4.y + 1e-16f;
        float ez = m4.z + 1e-16f, ew = m4.w + 1e-16f;
        float d = ex * k4.x + ey * k4.y + ez * k4.z + ew * k4.w;
        float q = ex * ex + ey * ey + ez * ez + ew * ew;
        #pragma unroll
        for (int off = 8; off > 0; off >>= 1) {
            d += __shfl_xor(d, off, 64);
            q += __shfl_xor(q, off, 64);
        }
        if (cg == 0) s_sc[n] = bet * d / (fmaxf(sqrtf(q), 1e-8f) * kden);
    }
    __syncthreads();

    // --- softmax over N (each thread owns indices t, t+512) ---
    float sc0 = s_sc[t], sc1 = s_sc[t + 512];
    float mx = block_max(fmaxf(sc0, sc1), s_tmp);
    float e0 = __expf(sc0 - mx), e1 = __expf(sc1 - mx);
    float inv = 1.0f / block_sum(e0 + e1, s_tmp);

    // --- interpolate ---
    const float omg = 1.0f - gb;
    s_sc[t]       = gb * e0 * inv + omg * wp0;
    s_sc[t + 512] = gb * e1 * inv + omg * wp1;
    __syncthreads();

    // --- shift (3-tap circular) + sharpen ---
    float wv0, wv1;
    {
        int nm = (t == 0) ? NN - 1 : t - 1;
        wv0 = powf(s0 * s_sc[nm] + s1 * s_sc[t] + s2 * s_sc[t + 1], gam);
    }
    {
        int n = t + 512;
        int np = (n == NN - 1) ? 0 : n + 1;
        wv1 = powf(s0 * s_sc[n - 1] + s1 * s_sc[n] + s2 * s_sc[np], gam);
    }
    float winv = 1.0f / (block_sum(wv0 + wv1, s_tmp) + 1e-16f);
    s_w[t]       = wv0 * winv;
    s_w[t + 512] = wv1 * winv;
    __syncthreads();

    // --- pass 2: read + erase/add purely from registers; fire-and-forget stores ---
    f32x4 acc = {0.f, 0.f, 0.f, 0.f};
    #pragma unroll
    for (int it = 0; it < ITS; ++it) {
        int n = it * 32 + rg;
        f32x4 m4 = mc[it];
        float wn = s_w[n];
        acc.x += wn * m4.x; acc.y += wn * m4.y;
        acc.z += wn * m4.z; acc.w += wn * m4.w;
        f32x4 o;
        o.x = m4.x * (1.0f - wn * e4.x) + wn * a4.x;
        o.y = m4.y * (1.0f - wn * e4.y) + wn * a4.y;
        o.z = m4.z * (1.0f - wn * e4.z) + wn * a4.z;
        o.w = m4.w * (1.0f - wn * e4.w) + wn * a4.w;
        __builtin_nontemporal_store(o, (f32x4*)(outb + (size_t)(n + 1) * MM + 4 * cg));
    }

    // --- reduce read accumulator; row 0 of outb = read ---
    const int wid = t >> 6, lane = t & 63;
    #pragma unroll
    for (int off = 16; off <= 32; off <<= 1) {
        acc.x += __shfl_xor(acc.x, off, 64);
        acc.y += __shfl_xor(acc.y, off, 64);
        acc.z += __shfl_xor(acc.z, off, 64);
        acc.w += __shfl_xor(acc.w, off, 64);
    }
    if (lane < 16) s_red[wid * 16 + lane] = acc;
    __syncthreads();
    if (t < 16) {
        f32x4 r = {0.f, 0.f, 0.f, 0.f};
        #pragma unroll
        for (int wv = 0; wv < NW; ++wv) {
            f32x4 v = s_red[wv * 16 + t];
            r.x += v.x; r.y += v.y; r.z += v.z; r.w += v.w;
        }
        __builtin_nontemporal_store(r, (f32x4*)(outb + 4 * t));
    }
}

extern "C" void kernel_launch(void* const* d_in, const int* in_sizes, int n_in,
                              void* d_out, int out_size, void* d_ws, size_t ws_size,
                              hipStream_t stream) {
    ntm_fused<<<NB, NT, 0, stream>>>(
        (const float*)d_in[0],  // memory (B,N,M)
        (const float*)d_in[1],  // k      (B,M)
        (const float*)d_in[2],  // beta   (B,1)
        (const float*)d_in[3],  // g      (B,1)
        (const float*)d_in[4],  // s      (B,3)
        (const float*)d_in[5],  // gamma  (B,1)
        (const float*)d_in[6],  // w_prev (B,N)
        (const float*)d_in[7],  // e      (B,M)
        (const float*)d_in[8],  // a      (B,M)
        (float*)d_out);
}